// Round 12
// baseline (155.397 us; speedup 1.0000x reference)
//
#include <hip/hip_runtime.h>

typedef unsigned short u16;
typedef unsigned int u32;
typedef __attribute__((ext_vector_type(8))) short bf16x8;    // 8 bf16 = 4 VGPRs
typedef __attribute__((ext_vector_type(16))) float f32x16;   // 32x32 C/D frag

__device__ __forceinline__ u16 f2bf(float f) {
  u32 u = __float_as_uint(f);
  u += 0x7fffu + ((u >> 16) & 1u);   // RNE
  return (u16)(u >> 16);
}

// ---------------- prep_small: W01 (64KB) and W23 (256KB), both L2-resident ----
__global__ void prep_small(const float* __restrict__ f0, const float* __restrict__ f1,
                           const float* __restrict__ f2, const float* __restrict__ f3,
                           float* __restrict__ W01, float* __restrict__ W23) {
  int b = blockIdx.x;
  if (b < 256) {
    int idx = b * 256 + threadIdx.x;           // 65536 = [o0][o1][i0][i1][r2]
    int r2 = idx & 15; int t = idx >> 4;
    int i1 = t & 7; t >>= 3;
    int i0 = t & 7; t >>= 3;
    int o1 = t & 7; int o0 = t >> 3;
    const float* a = f0 + (o0 * 8 + i0) * 16;          // stride r1 = 1
    const float* c = f1 + (o1 * 8 + i1) * 16 + r2;     // stride r1 = 1024
    float s = 0.f;
#pragma unroll
    for (int r1 = 0; r1 < 16; ++r1) s += a[r1] * c[r1 * 1024];
    W01[idx] = s;
  } else {
    int idx = (b - 256) * 256 + threadIdx.x;   // 65536 = [r2][o2][i2][o3][i3]
    int i3 = idx & 7, o3 = (idx >> 3) & 7, i2 = (idx >> 6) & 7;
    int o2 = (idx >> 9) & 7, r2 = idx >> 12;
    const float* a = f2 + ((r2 * 8 + o2) * 8 + i2) * 16;  // stride r3 = 1
    const float* c = f3 + o3 * 8 + i3;                    // stride r3 = 64
    float s = 0.f;
#pragma unroll
    for (int r3 = 0; r3 < 16; ++r3) s += a[r3] * c[r3 * 64];
    W23[idx] = s;
  }
}

// ---------------- prep_big: cvt x (blocks 0..8191) + build W (blocks 8192..12287)
__global__ void prep_big(const float* __restrict__ W01, const float* __restrict__ W23,
                         const float* __restrict__ x, u16* __restrict__ W,
                         uint4* __restrict__ xb) {
  int b = blockIdx.x;
  if (b < 8192) {
    int idx = b * 256 + threadIdx.x;           // 2,097,152 threads * 8 elems
    float4 a = ((const float4*)x)[idx * 2], d = ((const float4*)x)[idx * 2 + 1];
    union { u16 h[8]; uint4 v; } r;
    r.h[0] = f2bf(a.x); r.h[1] = f2bf(a.y); r.h[2] = f2bf(a.z); r.h[3] = f2bf(a.w);
    r.h[4] = f2bf(d.x); r.h[5] = f2bf(d.y); r.h[6] = f2bf(d.z); r.h[7] = f2bf(d.w);
    xb[idx] = r.v;
    return;
  }
  const int o = b - 8192;                      // 4096 rows
  const int o2 = (o >> 3) & 7, o3 = o & 7;
  const int tid = threadIdx.x;
  __shared__ float sW23[1024];                 // [r2][i2*8+i3]
  {
    int e = tid * 4;
    const float* src = W23 + (e >> 6) * 4096 + o2 * 512 + ((e >> 3) & 7) * 64
                         + o3 * 8 + (e & 7);
    ((float4*)sW23)[tid] = *(const float4*)src;
  }
  float w01r[16];
  {
    const float* a = W01 + (((o >> 6) * 64 + (tid >> 2)) << 4);
#pragma unroll
    for (int q = 0; q < 4; ++q) {
      float4 v = *(const float4*)(a + q * 4);
      w01r[q * 4] = v.x; w01r[q * 4 + 1] = v.y; w01r[q * 4 + 2] = v.z; w01r[q * 4 + 3] = v.w;
    }
  }
  __syncthreads();

  const int i2a = 2 * (tid & 3), i2b = i2a + 1;
  float acc[16] = {};
#pragma unroll
  for (int r2 = 0; r2 < 16; ++r2) {
    const float w = w01r[r2];
    const float4 va0 = *(const float4*)(sW23 + r2 * 64 + i2a * 8);
    const float4 va1 = *(const float4*)(sW23 + r2 * 64 + i2a * 8 + 4);
    const float4 vb0 = *(const float4*)(sW23 + r2 * 64 + i2b * 8);
    const float4 vb1 = *(const float4*)(sW23 + r2 * 64 + i2b * 8 + 4);
    acc[0]  += w * va0.x; acc[1]  += w * va0.y; acc[2]  += w * va0.z; acc[3]  += w * va0.w;
    acc[4]  += w * va1.x; acc[5]  += w * va1.y; acc[6]  += w * va1.z; acc[7]  += w * va1.w;
    acc[8]  += w * vb0.x; acc[9]  += w * vb0.y; acc[10] += w * vb0.z; acc[11] += w * vb0.w;
    acc[12] += w * vb1.x; acc[13] += w * vb1.y; acc[14] += w * vb1.z; acc[15] += w * vb1.w;
  }
  union { u16 h[8]; uint4 v; } r0, r1;
#pragma unroll
  for (int j = 0; j < 8; ++j) { r0.h[j] = f2bf(acc[j]); r1.h[j] = f2bf(acc[8 + j]); }
  uint4* dst = (uint4*)(W + (size_t)o * 4096 + tid * 16);
  dst[0] = r0.v; dst[1] = r1.v;
}

// ------ 256x256 8-wave bf16 GEMM: R11 structure + 32x32x16 MFMA ---------------
// R12 change (ONLY): 16x16x32 -> 32x32x16 MFMA.  MFMA wall per tile drops
// 64x19.4=1242 -> 32x32.3=1033 cyc (2382 vs 2075 TF ubench), MFMA count per
// wave halves (32->16) so each 32-cyc MFMA shadows 2x more ds_reads in the SGB
// interleave.  LDS bytes unchanged: per wave 8 A-frags + 4 B-frags b128/tile;
// read distribution with the existing ^((r>>1)&3) slot swizzle stays even
// (8 lanes per 4-bank group = LDS throughput floor, not a conflict).
// Frag layouts (32x32x16): A/B lane l holds row/col=l&31, k=(l>>5)*8+j.
// C/D (m74/m101 HW-verified): col=lane&31, row=(reg&3)+8*(reg>>2)+4*(lane>>5).
// Ring/publish/WAR invariants identical to R11 (4-slot ring, vmcnt(8), 1
// barrier/tile, reads of slot kt+1 in region kt legal since vmcnt(8) at B_{kt-1}
// completed stage(kt+1)).  Swizzle both-sides (rule #21).
__device__ __forceinline__ void gload_lds16(const void* g, void* l) {
  __builtin_amdgcn_global_load_lds((__attribute__((address_space(1))) void*)(g),
                                   (__attribute__((address_space(3))) void*)(l),
                                   16, 0, 0);
}

__global__ __launch_bounds__(512, 2) void gemm256(
    const u16* __restrict__ A, const u16* __restrict__ B,
    const float* __restrict__ bias, float* __restrict__ C) {
  constexpr int K = 4096, N = 4096, NT = 128;
  __shared__ u16 S[65536];                    // [slot4][A 8192 | B 8192]  128 KiB
  const int tid  = threadIdx.x;
  const int wave = tid >> 6, lane = tid & 63;
  const int l31 = lane & 31, l32 = lane >> 5;
  const int wr = wave >> 2, wc = wave & 3;    // 2 x 4 wave grid
  const int bm = (int)(blockIdx.x >> 4) * 256;
  const int bn = (int)(blockIdx.x & 15) * 256;

  // staging: thread covers row rl (of a 128-row half), phys 16B-slot tid&3
  const int rl = tid >> 2;
  const int ls = (tid & 3) ^ ((rl >> 1) & 3);          // pre-swizzled source slot
  const u16* srcA0 = A + (size_t)(bm +       rl) * K + ls * 8;
  const u16* srcA1 = A + (size_t)(bm + 128 + rl) * K + ls * 8;
  const u16* srcB0 = B + (size_t)(bn +       rl) * K + ls * 8;
  const u16* srcB1 = B + (size_t)(bn + 128 + rl) * K + ls * 8;
  const int dA0 = wave * 512,         dA1 = 4096  + wave * 512;   // wave-uniform
  const int dB0 = 8192 + wave * 512,  dB1 = 12288 + wave * 512;   // LDS dest (u16)

  // loop-invariant swizzled read offsets (u16 units within a slot)
  // A frag (mi,kk): row r = wr*128 + mi*32 + l31; logical slot = kk*2 + l32
  int offA[8], offB[4];
#pragma unroll
  for (int mi = 0; mi < 4; ++mi)
#pragma unroll
    for (int kk = 0; kk < 2; ++kk) {
      int r = wr * 128 + mi * 32 + l31;
      int sl = (kk * 2 + l32) ^ ((r >> 1) & 3);
      offA[mi * 2 + kk] = r * 32 + sl * 8;
    }
#pragma unroll
  for (int ni = 0; ni < 2; ++ni)
#pragma unroll
    for (int kk = 0; kk < 2; ++kk) {
      int r = wc * 64 + ni * 32 + l31;
      int sl = (kk * 2 + l32) ^ ((r >> 1) & 3);
      offB[ni * 2 + kk] = 8192 + r * 32 + sl * 8;
    }

#define STAGE_A(kts) do { int _s = (kts) & 3; u16* _b = S + _s * 16384;          \
    gload_lds16(srcA0 + (size_t)(kts) * 32, _b + dA0);                           \
    gload_lds16(srcA1 + (size_t)(kts) * 32, _b + dA1); } while (0)
#define STAGE_B(kts) do { int _s = (kts) & 3; u16* _b = S + _s * 16384;          \
    gload_lds16(srcB0 + (size_t)(kts) * 32, _b + dB0);                           \
    gload_lds16(srcB1 + (size_t)(kts) * 32, _b + dB1); } while (0)

// One K-tile, single region.  avU/bvU: this tile's operands (read last region).
// avL/bvL: next tile's, read this region from slot kt+1 (published).
// SGB per quarter: {DS 1, MFMA 1, DS 2, MFMA 1, VMEM 1, MFMA 2}
//   -> DS 12, MFMA 16, VMEM 4 per tile.
#define ITER(kt, avU, avL, bvU, bvL)                                             \
  {                                                                              \
    const u16* baseN = S + (((kt) + 1) & 3) * 16384;                             \
    const int kn = ((kt) + 3) & (NT - 1);                                        \
    _Pragma("unroll")                                                            \
    for (int i = 0; i < 8; ++i) avL[i] = *(const bf16x8*)(baseN + offA[i]);      \
    _Pragma("unroll")                                                            \
    for (int i = 0; i < 4; ++i) bvL[i] = *(const bf16x8*)(baseN + offB[i]);      \
    STAGE_A(kn); STAGE_B(kn);                                                    \
    _Pragma("unroll")                                                            \
    for (int kk = 0; kk < 2; ++kk)                                               \
      _Pragma("unroll")                                                          \
      for (int mi = 0; mi < 4; ++mi)                                             \
        _Pragma("unroll")                                                        \
        for (int ni = 0; ni < 2; ++ni)                                           \
          acc[mi][ni] = __builtin_amdgcn_mfma_f32_32x32x16_bf16(                 \
              avU[mi * 2 + kk], bvU[ni * 2 + kk], acc[mi][ni], 0, 0, 0);         \
    _Pragma("unroll")                                                            \
    for (int g = 0; g < 4; ++g) {                                                \
      __builtin_amdgcn_sched_group_barrier(0x100, 1, 0);  /* 1 ds_read  */       \
      __builtin_amdgcn_sched_group_barrier(0x008, 1, 0);  /* 1 mfma     */       \
      __builtin_amdgcn_sched_group_barrier(0x100, 2, 0);  /* 2 ds_read  */       \
      __builtin_amdgcn_sched_group_barrier(0x008, 1, 0);  /* 1 mfma     */       \
      __builtin_amdgcn_sched_group_barrier(0x070, 1, 0);  /* 1 stage    */       \
      __builtin_amdgcn_sched_group_barrier(0x008, 2, 0);  /* 2 mfma     */       \
    }                                                                            \
    asm volatile("s_waitcnt vmcnt(8)" ::: "memory");                             \
    __builtin_amdgcn_s_barrier();                                                \
  }

  // prologue: stage tiles 0,1,2; vmcnt(8) leaves tile2 in flight -> 0,1 landed
  STAGE_A(0); STAGE_B(0);
  STAGE_A(1); STAGE_B(1);
  STAGE_A(2); STAGE_B(2);
  asm volatile("s_waitcnt vmcnt(8)" ::: "memory");
  __builtin_amdgcn_s_barrier();

  f32x16 acc[4][2] = {};
  bf16x8 avE[8], avO[8], bvE[4], bvO[4];
#pragma unroll
  for (int i = 0; i < 8; ++i) avE[i] = *(const bf16x8*)(S + offA[i]);
#pragma unroll
  for (int i = 0; i < 4; ++i) bvE[i] = *(const bf16x8*)(S + offB[i]);

  for (int kt = 0; kt < NT; kt += 2) {
    ITER(kt,     avE, avO, bvE, bvO)
    ITER(kt + 1, avO, avE, bvO, bvE)
  }

  // epilogue (32x32 C/D): col = lane&31, row = (j&3) + 8*(j>>2) + 4*(lane>>5)
#pragma unroll
  for (int ni = 0; ni < 2; ++ni) {
    const int col = bn + wc * 64 + ni * 32 + l31;
    const float bvs = bias[col];
#pragma unroll
    for (int mi = 0; mi < 4; ++mi) {
      const int row0 = bm + wr * 128 + mi * 32 + l32 * 4;
#pragma unroll
      for (int j = 0; j < 16; ++j) {
        const int row = row0 + (j & 3) + 8 * (j >> 2);
        C[(size_t)row * N + col] = acc[mi][ni][j] + bvs;
      }
    }
  }
  // drain pending global_load_lds AFTER the epilogue (LDS may be reassigned)
  asm volatile("s_waitcnt vmcnt(0)" ::: "memory");
#undef STAGE_A
#undef STAGE_B
#undef ITER
}

// ---------------- launch ----------------
// d_ws: [0,32M) W bf16 ; [32M,64M) xb bf16
// d_out scratch (overwritten by gemm): [0,256KB) W01 f32 ; [256KB,1.25MB) W23 f32
extern "C" void kernel_launch(void* const* d_in, const int* in_sizes, int n_in,
                              void* d_out, int out_size, void* d_ws, size_t ws_size,
                              hipStream_t stream) {
  const float* x    = (const float*)d_in[0];
  const float* f0   = (const float*)d_in[1];
  const float* f1   = (const float*)d_in[2];
  const float* f2   = (const float*)d_in[3];
  const float* f3   = (const float*)d_in[4];
  const float* bias = (const float*)d_in[5];

  char* ws = (char*)d_ws;
  u16* Wb = (u16*)(ws);
  u16* xb = (u16*)(ws + 33554432);
  float* W01 = (float*)d_out;                 // d_out as temp; gemm overwrites all
  float* W23 = (float*)d_out + 65536;

  prep_small<<<512,   256, 0, stream>>>(f0, f1, f2, f3, W01, W23);
  prep_big  <<<12288, 256, 0, stream>>>(W01, W23, x, Wb, (uint4*)xb);
  gemm256   <<<256,   512, 0, stream>>>(xb, Wb, bias, (float*)d_out);
}

// Round 13
// 143.728 us; speedup vs baseline: 1.0812x; 1.0812x over previous
//
#include <hip/hip_runtime.h>

typedef unsigned short u16;
typedef unsigned int u32;
typedef __attribute__((ext_vector_type(8))) short bf16x8;   // 8 bf16 = 4 VGPRs
typedef __attribute__((ext_vector_type(4))) float f32x4;

__device__ __forceinline__ u16 f2bf(float f) {
  u32 u = __float_as_uint(f);
  u += 0x7fffu + ((u >> 16) & 1u);   // RNE
  return (u16)(u >> 16);
}

// ---------------- prep_small: W01 (64KB) and W23 (256KB), both L2-resident ----
__global__ void prep_small(const float* __restrict__ f0, const float* __restrict__ f1,
                           const float* __restrict__ f2, const float* __restrict__ f3,
                           float* __restrict__ W01, float* __restrict__ W23) {
  int b = blockIdx.x;
  if (b < 256) {
    int idx = b * 256 + threadIdx.x;           // 65536 = [o0][o1][i0][i1][r2]
    int r2 = idx & 15; int t = idx >> 4;
    int i1 = t & 7; t >>= 3;
    int i0 = t & 7; t >>= 3;
    int o1 = t & 7; int o0 = t >> 3;
    const float* a = f0 + (o0 * 8 + i0) * 16;          // stride r1 = 1
    const float* c = f1 + (o1 * 8 + i1) * 16 + r2;     // stride r1 = 1024
    float s = 0.f;
#pragma unroll
    for (int r1 = 0; r1 < 16; ++r1) s += a[r1] * c[r1 * 1024];
    W01[idx] = s;
  } else {
    int idx = (b - 256) * 256 + threadIdx.x;   // 65536 = [r2][o2][i2][o3][i3]
    int i3 = idx & 7, o3 = (idx >> 3) & 7, i2 = (idx >> 6) & 7;
    int o2 = (idx >> 9) & 7, r2 = idx >> 12;
    const float* a = f2 + ((r2 * 8 + o2) * 8 + i2) * 16;  // stride r3 = 1
    const float* c = f3 + o3 * 8 + i3;                    // stride r3 = 64
    float s = 0.f;
#pragma unroll
    for (int r3 = 0; r3 < 16; ++r3) s += a[r3] * c[r3 * 64];
    W23[idx] = s;
  }
}

// ---------------- prep_big: cvt x (blocks 0..8191) + build W (blocks 8192..12287)
__global__ void prep_big(const float* __restrict__ W01, const float* __restrict__ W23,
                         const float* __restrict__ x, u16* __restrict__ W,
                         uint4* __restrict__ xb) {
  int b = blockIdx.x;
  if (b < 8192) {
    int idx = b * 256 + threadIdx.x;           // 2,097,152 threads * 8 elems
    float4 a = ((const float4*)x)[idx * 2], d = ((const float4*)x)[idx * 2 + 1];
    union { u16 h[8]; uint4 v; } r;
    r.h[0] = f2bf(a.x); r.h[1] = f2bf(a.y); r.h[2] = f2bf(a.z); r.h[3] = f2bf(a.w);
    r.h[4] = f2bf(d.x); r.h[5] = f2bf(d.y); r.h[6] = f2bf(d.z); r.h[7] = f2bf(d.w);
    xb[idx] = r.v;
    return;
  }
  const int o = b - 8192;                      // 4096 rows
  const int o2 = (o >> 3) & 7, o3 = o & 7;
  const int tid = threadIdx.x;
  __shared__ float sW23[1024];                 // [r2][i2*8+i3]
  {
    int e = tid * 4;
    const float* src = W23 + (e >> 6) * 4096 + o2 * 512 + ((e >> 3) & 7) * 64
                         + o3 * 8 + (e & 7);
    ((float4*)sW23)[tid] = *(const float4*)src;
  }
  float w01r[16];
  {
    const float* a = W01 + (((o >> 6) * 64 + (tid >> 2)) << 4);
#pragma unroll
    for (int q = 0; q < 4; ++q) {
      float4 v = *(const float4*)(a + q * 4);
      w01r[q * 4] = v.x; w01r[q * 4 + 1] = v.y; w01r[q * 4 + 2] = v.z; w01r[q * 4 + 3] = v.w;
    }
  }
  __syncthreads();

  const int i2a = 2 * (tid & 3), i2b = i2a + 1;
  float acc[16] = {};
#pragma unroll
  for (int r2 = 0; r2 < 16; ++r2) {
    const float w = w01r[r2];
    const float4 va0 = *(const float4*)(sW23 + r2 * 64 + i2a * 8);
    const float4 va1 = *(const float4*)(sW23 + r2 * 64 + i2a * 8 + 4);
    const float4 vb0 = *(const float4*)(sW23 + r2 * 64 + i2b * 8);
    const float4 vb1 = *(const float4*)(sW23 + r2 * 64 + i2b * 8 + 4);
    acc[0]  += w * va0.x; acc[1]  += w * va0.y; acc[2]  += w * va0.z; acc[3]  += w * va0.w;
    acc[4]  += w * va1.x; acc[5]  += w * va1.y; acc[6]  += w * va1.z; acc[7]  += w * va1.w;
    acc[8]  += w * vb0.x; acc[9]  += w * vb0.y; acc[10] += w * vb0.z; acc[11] += w * vb0.w;
    acc[12] += w * vb1.x; acc[13] += w * vb1.y; acc[14] += w * vb1.z; acc[15] += w * vb1.w;
  }
  union { u16 h[8]; uint4 v; } r0, r1;
#pragma unroll
  for (int j = 0; j < 8; ++j) { r0.h[j] = f2bf(acc[j]); r1.h[j] = f2bf(acc[8 + j]); }
  uint4* dst = (uint4*)(W + (size_t)o * 4096 + tid * 16);
  dst[0] = r0.v; dst[1] = r1.v;
}

// ------ 256x256 8-wave bf16 GEMM, T19 interleave + 1 barrier/tile -------------
// R13 change (ONLY, vs R11): drop the ::: "memory" clobber from the counted
// vmcnt waits.  The clobber marks the INLINEASM mayLoad/mayStore, which makes
// SIInsertWaitcnts conservatively reset its counter model -> it emitted
// lgkmcnt(0) before the next iter's first MFMA, draining ALL 12 in-flight
// ds_reads (the ~774 cyc/tile residual over the 1408-cyc overlapped wall).
// Clobber-less volatile asm is the m201-verified pattern: identical runtime
// instruction, counted compiler lgkm waits survive.  Ordering stays safe: next
// iter's ds_reads are memory ops ordered by the raw s_barrier; MFMA operand
// waits are compiler-counted.
// Structure (R11, verified 116.4us / 57% MfmaUtil / 0 conflicts): one region
// per K-tile, SGB interleave {DS 3, MFMA 4, VMEM 1}-ish x4, 4-slot LDS ring,
// vmcnt(8) publish (slots kt+1,kt+2 readable after B_kt), stage kt+3 over
// slot kt-1 (WAR safe).  Swizzle both-sides (rule #21): phys = log^((r>>1)&3).
__device__ __forceinline__ void gload_lds16(const void* g, void* l) {
  __builtin_amdgcn_global_load_lds((__attribute__((address_space(1))) void*)(g),
                                   (__attribute__((address_space(3))) void*)(l),
                                   16, 0, 0);
}

__global__ __launch_bounds__(512, 2) void gemm256(
    const u16* __restrict__ A, const u16* __restrict__ B,
    const float* __restrict__ bias, float* __restrict__ C) {
  constexpr int K = 4096, N = 4096, NT = 128;
  __shared__ u16 S[65536];                    // [slot4][A 8192 | B 8192]  128 KiB
  const int tid  = threadIdx.x;
  const int wave = tid >> 6, lane = tid & 63;
  const int l15 = lane & 15, l4 = lane >> 4;
  const int wr = wave >> 2, wc = wave & 3;    // 2 x 4 wave grid
  const int bm = (int)(blockIdx.x >> 4) * 256;
  const int bn = (int)(blockIdx.x & 15) * 256;

  // staging: thread covers row rl (of a 128-row half), phys 16B-slot tid&3
  const int rl = tid >> 2;
  const int ls = (tid & 3) ^ ((rl >> 1) & 3);          // pre-swizzled source slot
  const u16* srcA0 = A + (size_t)(bm +       rl) * K + ls * 8;
  const u16* srcA1 = A + (size_t)(bm + 128 + rl) * K + ls * 8;
  const u16* srcB0 = B + (size_t)(bn +       rl) * K + ls * 8;
  const u16* srcB1 = B + (size_t)(bn + 128 + rl) * K + ls * 8;
  const int dA0 = wave * 512,         dA1 = 4096  + wave * 512;   // wave-uniform
  const int dB0 = 8192 + wave * 512,  dB1 = 12288 + wave * 512;   // LDS dest (u16)

  // loop-invariant swizzled read offsets (u16 units within a slot)
  int offA[8], offB[4];
#pragma unroll
  for (int mi = 0; mi < 8; ++mi) {
    int r = wr * 128 + mi * 16 + l15;
    offA[mi] = r * 32 + ((l4 ^ ((r >> 1) & 3)) * 8);
  }
#pragma unroll
  for (int ni = 0; ni < 4; ++ni) {
    int r = wc * 64 + ni * 16 + l15;
    offB[ni] = 8192 + r * 32 + ((l4 ^ ((r >> 1) & 3)) * 8);
  }

#define STAGE_A(kts) do { int _s = (kts) & 3; u16* _b = S + _s * 16384;          \
    gload_lds16(srcA0 + (size_t)(kts) * 32, _b + dA0);                           \
    gload_lds16(srcA1 + (size_t)(kts) * 32, _b + dA1); } while (0)
#define STAGE_B(kts) do { int _s = (kts) & 3; u16* _b = S + _s * 16384;          \
    gload_lds16(srcB0 + (size_t)(kts) * 32, _b + dB0);                           \
    gload_lds16(srcB1 + (size_t)(kts) * 32, _b + dB1); } while (0)

// One K-tile, single region.  avU/bvU: this tile's Q0 operands (read last
// region).  avL/bvL: next tile's, read this region from slot kt+1 (published).
// avN: this tile's mi4-7, consumed by Q1 mid-region.
// SGB pattern per quarter: {DS 1, MFMA 2, DS 2, MFMA 2, VMEM 1, MFMA 4}
//   -> DS 12, MFMA 32, VMEM 4 total; reads feed Q1/next-tile just in time.
#define ITER(kt, avU, avL, bvU, bvL)                                             \
  {                                                                              \
    const u16* base  = S + ((kt) & 3) * 16384;                                   \
    const u16* baseN = S + (((kt) + 1) & 3) * 16384;                             \
    const int kn = ((kt) + 3) & (NT - 1);                                        \
    bf16x8 avN[4];                                                               \
    _Pragma("unroll")                                                            \
    for (int i = 0; i < 4; ++i) avN[i] = *(const bf16x8*)(base + offA[4 + i]);   \
    _Pragma("unroll")                                                            \
    for (int i = 0; i < 4; ++i) avL[i] = *(const bf16x8*)(baseN + offA[i]);      \
    _Pragma("unroll")                                                            \
    for (int i = 0; i < 4; ++i) bvL[i] = *(const bf16x8*)(baseN + offB[i]);      \
    STAGE_A(kn); STAGE_B(kn);                                                    \
    _Pragma("unroll")                                                            \
    for (int mi = 0; mi < 4; ++mi)                                               \
      _Pragma("unroll")                                                          \
      for (int ni = 0; ni < 4; ++ni)                                             \
        acc[mi][ni] = __builtin_amdgcn_mfma_f32_16x16x32_bf16(                   \
            avU[mi], bvU[ni], acc[mi][ni], 0, 0, 0);                             \
    _Pragma("unroll")                                                            \
    for (int mi = 0; mi < 4; ++mi)                                               \
      _Pragma("unroll")                                                          \
      for (int ni = 0; ni < 4; ++ni)                                             \
        acc[4 + mi][ni] = __builtin_amdgcn_mfma_f32_16x16x32_bf16(               \
            avN[mi], bvU[ni], acc[4 + mi][ni], 0, 0, 0);                         \
    _Pragma("unroll")                                                            \
    for (int g = 0; g < 4; ++g) {                                                \
      __builtin_amdgcn_sched_group_barrier(0x100, 1, 0);  /* 1 ds_read  */       \
      __builtin_amdgcn_sched_group_barrier(0x008, 2, 0);  /* 2 mfma     */       \
      __builtin_amdgcn_sched_group_barrier(0x100, 2, 0);  /* 2 ds_read  */       \
      __builtin_amdgcn_sched_group_barrier(0x008, 2, 0);  /* 2 mfma     */       \
      __builtin_amdgcn_sched_group_barrier(0x070, 1, 0);  /* 1 stage    */       \
      __builtin_amdgcn_sched_group_barrier(0x008, 4, 0);  /* 4 mfma     */       \
    }                                                                            \
    asm volatile("s_waitcnt vmcnt(8)");   /* clobber-less: counted waits live */ \
    __builtin_amdgcn_s_barrier();                                                \
  }

  // prologue: stage tiles 0,1,2; vmcnt(8) leaves tile2 in flight -> 0,1 landed
  STAGE_A(0); STAGE_B(0);
  STAGE_A(1); STAGE_B(1);
  STAGE_A(2); STAGE_B(2);
  asm volatile("s_waitcnt vmcnt(8)");
  __builtin_amdgcn_s_barrier();

  f32x4 acc[8][4] = {};
  bf16x8 avE[4], avO[4], bvE[4], bvO[4];
#pragma unroll
  for (int i = 0; i < 4; ++i) avE[i] = *(const bf16x8*)(S + offA[i]);
#pragma unroll
  for (int i = 0; i < 4; ++i) bvE[i] = *(const bf16x8*)(S + offB[i]);

  for (int kt = 0; kt < NT; kt += 2) {
    ITER(kt,     avE, avO, bvE, bvO)
    ITER(kt + 1, avO, avE, bvO, bvE)
  }

  // epilogue: C row = (lane>>4)*4 + j (M side), col = lane&15 (N side)
#pragma unroll
  for (int ni = 0; ni < 4; ++ni) {
    const int col = bn + wc * 64 + ni * 16 + l15;
    const float bvs = bias[col];
#pragma unroll
    for (int mi = 0; mi < 8; ++mi) {
      const int row0 = bm + wr * 128 + mi * 16 + l4 * 4;
#pragma unroll
      for (int j = 0; j < 4; ++j)
        C[(size_t)(row0 + j) * N + col] = acc[mi][ni][j] + bvs;
    }
  }
  // drain pending global_load_lds AFTER the epilogue (LDS may be reassigned)
  asm volatile("s_waitcnt vmcnt(0)" ::: "memory");
#undef STAGE_A
#undef STAGE_B
#undef ITER
}

// ---------------- launch ----------------
// d_ws: [0,32M) W bf16 ; [32M,64M) xb bf16
// d_out scratch (overwritten by gemm): [0,256KB) W01 f32 ; [256KB,1.25MB) W23 f32
extern "C" void kernel_launch(void* const* d_in, const int* in_sizes, int n_in,
                              void* d_out, int out_size, void* d_ws, size_t ws_size,
                              hipStream_t stream) {
  const float* x    = (const float*)d_in[0];
  const float* f0   = (const float*)d_in[1];
  const float* f1   = (const float*)d_in[2];
  const float* f2   = (const float*)d_in[3];
  const float* f3   = (const float*)d_in[4];
  const float* bias = (const float*)d_in[5];

  char* ws = (char*)d_ws;
  u16* Wb = (u16*)(ws);
  u16* xb = (u16*)(ws + 33554432);
  float* W01 = (float*)d_out;                 // d_out as temp; gemm overwrites all
  float* W23 = (float*)d_out + 65536;

  prep_small<<<512,   256, 0, stream>>>(f0, f1, f2, f3, W01, W23);
  prep_big  <<<12288, 256, 0, stream>>>(W01, W23, x, Wb, (uint4*)xb);
  gemm256   <<<256,   512, 0, stream>>>(xb, Wb, bias, (float*)d_out);
}